// Round 1
// baseline (679.169 us; speedup 1.0000x reference)
//
#include <hip/hip_runtime.h>
#include <cstdint>
#include <cstddef>

// Problem constants: B=32, LQ=LA=1024, H=512
#define NB   32
#define LQA  1024   // LQ == LA
#define HD   512

typedef __attribute__((ext_vector_type(4))) float  f32x4;
typedef __attribute__((ext_vector_type(8))) short  s16x8;   // 8 bf16 (4 VGPRs) MFMA frag
typedef __attribute__((ext_vector_type(4))) unsigned short u16x4;

static __device__ __forceinline__ unsigned short f2bf(float f) {
  unsigned int u = __builtin_bit_cast(unsigned int, f);
  u += 0x7fffu + ((u >> 16) & 1u);      // RNE
  return (unsigned short)(u >> 16);
}
static __device__ __forceinline__ float bf2f(unsigned short h) {
  unsigned int u = ((unsigned int)h) << 16;
  return __builtin_bit_cast(float, u);
}
static __device__ __forceinline__ u16x4 cvt4(f32x4 v) {
  u16x4 r;
  r.x = f2bf(v.x); r.y = f2bf(v.y); r.z = f2bf(v.z); r.w = f2bf(v.w);
  return r;
}

// ---------------------------------------------------------------------------
// K0: per-batch 64x64 tiled transpose fp32 [LQA x HD] -> bf16 [HD x LQA],
//     and copy the fp32 tile into the concat-output left half (row stride 1024).
// grid: (HD/64=8, LQA/64=16, NB), block 256
// ---------------------------------------------------------------------------
__global__ __launch_bounds__(256) void k_transpose_copy(
    const float* __restrict__ src,        // [NB][LQA][HD]
    float* __restrict__ out_left,         // [NB][LQA][1024], cols 0..511
    unsigned short* __restrict__ dstT)    // [NB][HD][LQA] bf16
{
  const int b  = blockIdx.z;
  const int h0 = blockIdx.x * 64;
  const int q0 = blockIdx.y * 64;
  const int t  = threadIdx.x;

  __shared__ unsigned short T[64 * 68];   // pad 4 to break conflicts a bit

  const float* sb = src + (size_t)b * LQA * HD;
  float* ob       = out_left + (size_t)b * LQA * 1024;
  unsigned short* db = dstT + (size_t)b * HD * LQA;

#pragma unroll
  for (int j = 0; j < 4; ++j) {
    int f = t + 256 * j;
    int r = f >> 4;            // 0..63 (q-local)
    int c = (f & 15) * 4;      // 0..60 (h-local)
    f32x4 v = *(const f32x4*)(sb + (size_t)(q0 + r) * HD + h0 + c);
    *(f32x4*)(ob + (size_t)(q0 + r) * 1024 + h0 + c) = v;   // concat left half
    *(u16x4*)&T[r * 68 + c] = cvt4(v);
  }
  __syncthreads();
#pragma unroll
  for (int j = 0; j < 4; ++j) {
    int f = t + 256 * j;
    int orow = f >> 4;         // 0..63 (h-local)
    int c = (f & 15) * 4;      // 0..60 (q-local)
    u16x4 v;
    v.x = T[(c + 0) * 68 + orow];
    v.y = T[(c + 1) * 68 + orow];
    v.z = T[(c + 2) * 68 + orow];
    v.w = T[(c + 3) * 68 + orow];
    *(u16x4*)&db[(size_t)(h0 + orow) * LQA + q0 + c] = v;
  }
}

// ---------------------------------------------------------------------------
// K1: scores. E[b,q,a] = mask * exp(temp * dot(q[b,q,:], a[b,a,:]))
// 128x128 tile MFMA bf16 GEMM (BT layout), VALU staging fp32->bf16.
// Epilogue writes E and E^T (both coalesced through LDS).
// grid: (8 mt, 8 nt, NB), block 256 (4 waves, 2x2 of 64x64)
// ---------------------------------------------------------------------------
__global__ __launch_bounds__(256) void k_scores(
    const float* __restrict__ q, const float* __restrict__ a,
    const int* __restrict__ qmask, const int* __restrict__ amask,
    const float* __restrict__ temp_p,
    unsigned short* __restrict__ E, unsigned short* __restrict__ ET)
{
  const int b  = blockIdx.z;
  const int m0 = blockIdx.x * 128;
  const int n0 = blockIdx.y * 128;
  const int t  = threadIdx.x;
  const int lane = t & 63;
  const int w  = t >> 6;
  const int moff = (w & 1) * 64;
  const int noff = (w >> 1) * 64;
  const int lrow = lane & 15;
  const int quad = lane >> 4;

  __shared__ unsigned short As[128 * 32];
  __shared__ unsigned short Bs[128 * 32];
  __shared__ unsigned short Cs[128 * 132];   // 8B-aligned rows, tolerable xpose conflicts

  const float* qb = q + (size_t)b * LQA * HD;
  const float* ab = a + (size_t)b * LQA * HD;

  f32x4 acc[4][4];
#pragma unroll
  for (int i = 0; i < 4; ++i)
#pragma unroll
    for (int j = 0; j < 4; ++j) acc[i][j] = (f32x4)0.f;

  for (int kt = 0; kt < HD / 32; ++kt) {
#pragma unroll
    for (int j = 0; j < 4; ++j) {
      int f = t + 256 * j;
      int row = f >> 3;          // 0..127
      int ch  = f & 7;           // 0..7 -> k chunk of 4
      f32x4 va = *(const f32x4*)(qb + (size_t)(m0 + row) * HD + kt * 32 + ch * 4);
      f32x4 vb = *(const f32x4*)(ab + (size_t)(n0 + row) * HD + kt * 32 + ch * 4);
      *(u16x4*)&As[row * 32 + ch * 4] = cvt4(va);
      *(u16x4*)&Bs[row * 32 + ch * 4] = cvt4(vb);
    }
    __syncthreads();
    s16x8 af[4], bfr[4];
#pragma unroll
    for (int i = 0; i < 4; ++i) {
      af[i]  = *(const s16x8*)&As[(moff + i * 16 + lrow) * 32 + quad * 8];
      bfr[i] = *(const s16x8*)&Bs[(noff + i * 16 + lrow) * 32 + quad * 8];
    }
#pragma unroll
    for (int i = 0; i < 4; ++i)
#pragma unroll
      for (int j = 0; j < 4; ++j)
        acc[i][j] = __builtin_amdgcn_mfma_f32_16x16x32_bf16(af[i], bfr[j], acc[i][j], 0, 0, 0);
    __syncthreads();
  }

  // Epilogue: temp/mask/exp -> Cs (bf16), then coalesced E and E^T writes.
  const float temp = temp_p[0];
  const int* qmb = qmask + b * LQA;
  const int* amb = amask + b * LQA;
#pragma unroll
  for (int i = 0; i < 4; ++i) {
#pragma unroll
    for (int j = 0; j < 4; ++j) {
      int ncol = noff + j * 16 + lrow;
      float am = (amb[n0 + ncol] != 0) ? 1.f : 0.f;
#pragma unroll
      for (int r = 0; r < 4; ++r) {
        int mrow = moff + i * 16 + quad * 4 + r;
        float qm = (qmb[m0 + mrow] != 0) ? 1.f : 0.f;
        float e = __expf(acc[i][j][r] * temp) * am * qm;
        Cs[mrow * 132 + ncol] = f2bf(e);
      }
    }
  }
  __syncthreads();
  const size_t Ebase = (size_t)b * LQA * LQA;
#pragma unroll
  for (int jj = 0; jj < 16; ++jj) {
    int f = t + 256 * jj;
    int row = f >> 5;            // 0..127
    int c = (f & 31) * 4;        // 0..124
    u16x4 v = *(const u16x4*)&Cs[row * 132 + c];
    *(u16x4*)&E[Ebase + (size_t)(m0 + row) * LQA + n0 + c] = v;
  }
#pragma unroll
  for (int jj = 0; jj < 16; ++jj) {
    int f = t + 256 * jj;
    int orow = f >> 5;           // a-local
    int c = (f & 31) * 4;        // q-local
    u16x4 v;
    v.x = Cs[(c + 0) * 132 + orow];
    v.y = Cs[(c + 1) * 132 + orow];
    v.z = Cs[(c + 2) * 132 + orow];
    v.w = Cs[(c + 3) * 132 + orow];
    *(u16x4*)&ET[Ebase + (size_t)(n0 + orow) * LQA + m0 + c] = v;
  }
}

// ---------------------------------------------------------------------------
// K2: row sums of a bf16 [NB*LQA x LQA] matrix -> (inv, add) per row.
// inv = 1/sum, add = 0 if sum>0 else inv=0, add=1/1024 (all-masked uniform case)
// 16 rows per 256-block.
// ---------------------------------------------------------------------------
__global__ __launch_bounds__(256) void k_rowsum(
    const unsigned short* __restrict__ Emat, float2* __restrict__ invadd)
{
  const int t = threadIdx.x;
  const int rowg = blockIdx.x * 16 + (t >> 4);
  const int s = t & 15;
  const unsigned short* rp = Emat + (size_t)rowg * LQA;
  float sum = 0.f;
#pragma unroll
  for (int it = 0; it < 16; ++it) {
    u16x4 v = *(const u16x4*)&rp[it * 64 + s * 4];
    sum += bf2f(v.x) + bf2f(v.y) + bf2f(v.z) + bf2f(v.w);
  }
  sum += __shfl_xor(sum, 1);
  sum += __shfl_xor(sum, 2);
  sum += __shfl_xor(sum, 4);
  sum += __shfl_xor(sum, 8);
  if (s == 0) {
    float2 o;
    if (sum > 0.f) { o.x = 1.f / sum; o.y = 0.f; }
    else           { o.x = 0.f;       o.y = 1.f / 1024.f; }
    invadd[rowg] = o;
  }
}

// ---------------------------------------------------------------------------
// K3: aggregation GEMM. C[m,h] = sum_k (Emat[m,k]*inv[m]+add[m]) * Bt[h,k]
// Emat: [NB][LQA][LQA] bf16 (E or E^T), Bt: [NB][HD][LQA] bf16 (aT or qT).
// Writes fp32 into out right-half: out[b, m, 512+h].
// grid: (8 mt, 4 nt, NB), block 256
// ---------------------------------------------------------------------------
__global__ __launch_bounds__(256) void k_agg(
    const unsigned short* __restrict__ Emat,
    const unsigned short* __restrict__ Bt,
    const float2* __restrict__ invadd,
    float* __restrict__ outp)
{
  const int b  = blockIdx.z;
  const int m0 = blockIdx.x * 128;
  const int n0 = blockIdx.y * 128;   // h tile (< 512)
  const int t  = threadIdx.x;
  const int lane = t & 63;
  const int w  = t >> 6;
  const int moff = (w & 1) * 64;
  const int noff = (w >> 1) * 64;
  const int lrow = lane & 15;
  const int quad = lane >> 4;

  __shared__ unsigned short As[128 * 32];
  __shared__ unsigned short Bs[128 * 32];

  const unsigned short* Eb = Emat + (size_t)b * LQA * LQA;
  const unsigned short* Bb = Bt + (size_t)b * HD * LQA;
  const float2* ia = invadd + b * LQA;

  // staged rows per thread are fixed across k-iters: hoist inv/add
  float inv_r[4], add_r[4];
#pragma unroll
  for (int j = 0; j < 4; ++j) {
    int row = (t >> 3) + 32 * j;
    float2 v = ia[m0 + row];
    inv_r[j] = v.x; add_r[j] = v.y;
  }

  f32x4 acc[4][4];
#pragma unroll
  for (int i = 0; i < 4; ++i)
#pragma unroll
    for (int j = 0; j < 4; ++j) acc[i][j] = (f32x4)0.f;

  for (int kt = 0; kt < LQA / 32; ++kt) {
#pragma unroll
    for (int j = 0; j < 4; ++j) {
      int f = t + 256 * j;
      int row = f >> 3;
      int ch  = f & 7;
      u16x4 ev = *(const u16x4*)&Eb[(size_t)(m0 + row) * LQA + kt * 32 + ch * 4];
      f32x4 p;
      p.x = bf2f(ev.x) * inv_r[j] + add_r[j];
      p.y = bf2f(ev.y) * inv_r[j] + add_r[j];
      p.z = bf2f(ev.z) * inv_r[j] + add_r[j];
      p.w = bf2f(ev.w) * inv_r[j] + add_r[j];
      *(u16x4*)&As[row * 32 + ch * 4] = cvt4(p);
      u16x4 bv = *(const u16x4*)&Bb[(size_t)(n0 + row) * LQA + kt * 32 + ch * 4];
      *(u16x4*)&Bs[row * 32 + ch * 4] = bv;
    }
    __syncthreads();
    s16x8 af[4], bfr[4];
#pragma unroll
    for (int i = 0; i < 4; ++i) {
      af[i]  = *(const s16x8*)&As[(moff + i * 16 + lrow) * 32 + quad * 8];
      bfr[i] = *(const s16x8*)&Bs[(noff + i * 16 + lrow) * 32 + quad * 8];
    }
#pragma unroll
    for (int i = 0; i < 4; ++i)
#pragma unroll
      for (int j = 0; j < 4; ++j)
        acc[i][j] = __builtin_amdgcn_mfma_f32_16x16x32_bf16(af[i], bfr[j], acc[i][j], 0, 0, 0);
    __syncthreads();
  }

  // Epilogue: fp32 stores into concat right half (row stride 1024, col offset 512)
#pragma unroll
  for (int i = 0; i < 4; ++i) {
#pragma unroll
    for (int j = 0; j < 4; ++j) {
      int ncol = noff + j * 16 + lrow;
#pragma unroll
      for (int r = 0; r < 4; ++r) {
        int mrow = moff + i * 16 + quad * 4 + r;
        outp[(size_t)b * LQA * 1024 + (size_t)(m0 + mrow) * 1024 + 512 + n0 + ncol] =
            acc[i][j][r];
      }
    }
  }
}

// ---------------------------------------------------------------------------
extern "C" void kernel_launch(void* const* d_in, const int* in_sizes, int n_in,
                              void* d_out, int out_size, void* d_ws, size_t ws_size,
                              hipStream_t stream) {
  const float* q    = (const float*)d_in[0];
  const float* a    = (const float*)d_in[1];
  const int*   qm   = (const int*)d_in[2];
  const int*   am   = (const int*)d_in[3];
  const float* temp = (const float*)d_in[4];

  float* out0 = (float*)d_out;                         // [NB][LQA][1024] concat(q, q_s)
  float* out1 = out0 + (size_t)NB * LQA * 1024;        // [NB][LQA][1024] concat(a, a_s)

  char* ws = (char*)d_ws;
  const size_t MB = 1024ull * 1024ull;
  unsigned short* E    = (unsigned short*)(ws);                 // 64 MB
  unsigned short* ET   = (unsigned short*)(ws + 64 * MB);       // 64 MB
  unsigned short* qT   = (unsigned short*)(ws + 128 * MB);      // 32 MB
  unsigned short* aT   = (unsigned short*)(ws + 160 * MB);      // 32 MB
  float2* invq = (float2*)(ws + 192 * MB);                      // 256 KB
  float2* inva = (float2*)(ws + 192 * MB + 262144);             // 256 KB
  // total ws use: ~192.5 MB

  k_transpose_copy<<<dim3(8, 16, NB), 256, 0, stream>>>(q, out0, qT);
  k_transpose_copy<<<dim3(8, 16, NB), 256, 0, stream>>>(a, out1, aT);
  k_scores<<<dim3(8, 8, NB), 256, 0, stream>>>(q, a, qm, am, temp, E, ET);
  k_rowsum<<<dim3(NB * LQA / 16), 256, 0, stream>>>(E, invq);   // sums over a -> per-q
  k_rowsum<<<dim3(NB * LQA / 16), 256, 0, stream>>>(ET, inva);  // sums over q -> per-a
  k_agg<<<dim3(8, 4, NB), 256, 0, stream>>>(E,  aT, invq, out0);  // q_s
  k_agg<<<dim3(8, 4, NB), 256, 0, stream>>>(ET, qT, inva, out1);  // a_s
}

// Round 2
// 628.173 us; speedup vs baseline: 1.0812x; 1.0812x over previous
//
#include <hip/hip_runtime.h>
#include <cstdint>
#include <cstddef>

// Problem constants: B=32, LQ=LA=1024, H=512
#define NB   32
#define LQA  1024   // LQ == LA
#define HD   512

typedef __attribute__((ext_vector_type(4))) float  f32x4;
typedef __attribute__((ext_vector_type(8))) short  s16x8;   // 8 bf16 (4 VGPRs) MFMA frag
typedef __attribute__((ext_vector_type(4))) unsigned short u16x4;

static __device__ __forceinline__ unsigned short f2bf(float f) {
  unsigned int u = __builtin_bit_cast(unsigned int, f);
  u += 0x7fffu + ((u >> 16) & 1u);      // RNE
  return (unsigned short)(u >> 16);
}
static __device__ __forceinline__ float bf2f(unsigned short h) {
  unsigned int u = ((unsigned int)h) << 16;
  return __builtin_bit_cast(float, u);
}
static __device__ __forceinline__ u16x4 cvt4(f32x4 v) {
  u16x4 r;
  r.x = f2bf(v.x); r.y = f2bf(v.y); r.z = f2bf(v.z); r.w = f2bf(v.w);
  return r;
}

// async global->LDS, 16B per lane; lds base must be wave-uniform (HW scatters
// lane i at base + i*16)
typedef __attribute__((address_space(1))) const void gas_void;
typedef __attribute__((address_space(3))) void las_void;
static __device__ __forceinline__ void gload_lds16(const void* g, void* l) {
  __builtin_amdgcn_global_load_lds((gas_void*)g, (las_void*)l, 16, 0, 0);
}

// ---------------------------------------------------------------------------
// K0: per-batch 64x64 tiled: fp32 [LQA x HD] ->
//   (a) fp32 copy into concat-output left half,
//   (b) bf16 transposed copy [HD x LQA]  (for aggregation-GEMM B operands),
//   (c) bf16 row-major copy [LQA x HD]   (for score-GEMM operands).
// grid: (HD/64=8, LQA/64=16, NB), block 256
// ---------------------------------------------------------------------------
__global__ __launch_bounds__(256) void k_transpose_copy(
    const float* __restrict__ src,        // [NB][LQA][HD]
    float* __restrict__ out_left,         // [NB][LQA][1024], cols 0..511
    unsigned short* __restrict__ dstT,    // [NB][HD][LQA] bf16
    unsigned short* __restrict__ dstN)    // [NB][LQA][HD] bf16
{
  const int b  = blockIdx.z;
  const int h0 = blockIdx.x * 64;
  const int q0 = blockIdx.y * 64;
  const int t  = threadIdx.x;

  __shared__ unsigned short T[64 * 68];

  const float* sb = src + (size_t)b * LQA * HD;
  float* ob       = out_left + (size_t)b * LQA * 1024;
  unsigned short* db  = dstT + (size_t)b * HD * LQA;
  unsigned short* dbn = dstN + (size_t)b * LQA * HD;

#pragma unroll
  for (int j = 0; j < 4; ++j) {
    int f = t + 256 * j;
    int r = f >> 4;            // 0..63 (q-local)
    int c = (f & 15) * 4;      // 0..60 (h-local)
    f32x4 v = *(const f32x4*)(sb + (size_t)(q0 + r) * HD + h0 + c);
    *(f32x4*)(ob + (size_t)(q0 + r) * 1024 + h0 + c) = v;   // concat left half
    u16x4 cv = cvt4(v);
    *(u16x4*)&dbn[(size_t)(q0 + r) * HD + h0 + c] = cv;     // row-major bf16
    *(u16x4*)&T[r * 68 + c] = cv;
  }
  __syncthreads();
#pragma unroll
  for (int j = 0; j < 4; ++j) {
    int f = t + 256 * j;
    int orow = f >> 4;         // 0..63 (h-local)
    int c = (f & 15) * 4;      // 0..60 (q-local)
    u16x4 v;
    v.x = T[(c + 0) * 68 + orow];
    v.y = T[(c + 1) * 68 + orow];
    v.z = T[(c + 2) * 68 + orow];
    v.w = T[(c + 3) * 68 + orow];
    *(u16x4*)&db[(size_t)(h0 + orow) * LQA + q0 + c] = v;
  }
}

// ---------------------------------------------------------------------------
// K1: scores. E[b,q,a] = qm*am*exp(temp * dot(q,a)); writes E and E^T (bf16).
// 128x128 tile, BK=32, global_load_lds(16B) staging from bf16 copies.
// grid: (8 mt, 8 nt, NB), block 256 (4 waves, 2x2 of 64x64)
// ---------------------------------------------------------------------------
__global__ __launch_bounds__(256) void k_scores(
    const unsigned short* __restrict__ qb16, const unsigned short* __restrict__ ab16,
    const int* __restrict__ qmask, const int* __restrict__ amask,
    const float* __restrict__ temp_p,
    unsigned short* __restrict__ E, unsigned short* __restrict__ ET)
{
  const int b  = blockIdx.z;
  const int m0 = blockIdx.x * 128;
  const int n0 = blockIdx.y * 128;
  const int t  = threadIdx.x;
  const int lane = t & 63;
  const int w  = t >> 6;
  const int moff = (w & 1) * 64;
  const int noff = (w >> 1) * 64;
  const int lrow = lane & 15;
  const int quad = lane >> 4;

  // As/Bs (8KB each) alias the epilogue Cs buffer (128*132 ushort = 33.8KB)
  __shared__ __align__(16) unsigned short smem[128 * 132];
  unsigned short* As = smem;          // [128][32]
  unsigned short* Bs = smem + 4096;   // [128][32]

  const unsigned short* qb = qb16 + (size_t)b * LQA * HD;
  const unsigned short* ab = ab16 + (size_t)b * LQA * HD;

  // staging: chunk f covers row f>>2, k-chunk (f&3)*8; pass p: f = t + 256*p
  const int fa = t, fb = t + 256;
  const unsigned short* qg0 = qb + (size_t)(m0 + (fa >> 2)) * HD + (fa & 3) * 8;
  const unsigned short* qg1 = qb + (size_t)(m0 + (fb >> 2)) * HD + (fb & 3) * 8;
  const unsigned short* ag0 = ab + (size_t)(n0 + (fa >> 2)) * HD + (fa & 3) * 8;
  const unsigned short* ag1 = ab + (size_t)(n0 + (fb >> 2)) * HD + (fb & 3) * 8;
  unsigned short* As0 = As + w * 512;          // wave-uniform LDS bases
  unsigned short* As1 = As + (4 + w) * 512;
  unsigned short* Bs0 = Bs + w * 512;
  unsigned short* Bs1 = Bs + (4 + w) * 512;

  f32x4 acc[4][4];
#pragma unroll
  for (int i = 0; i < 4; ++i)
#pragma unroll
    for (int j = 0; j < 4; ++j) acc[i][j] = (f32x4)0.f;

  for (int kt = 0; kt < HD / 32; ++kt) {
    const int ko = kt * 32;
    gload_lds16(qg0 + ko, As0);
    gload_lds16(qg1 + ko, As1);
    gload_lds16(ag0 + ko, Bs0);
    gload_lds16(ag1 + ko, Bs1);
    __syncthreads();
    s16x8 af[4], bfr[4];
#pragma unroll
    for (int i = 0; i < 4; ++i) {
      af[i]  = *(const s16x8*)&As[(moff + i * 16 + lrow) * 32 + quad * 8];
      bfr[i] = *(const s16x8*)&Bs[(noff + i * 16 + lrow) * 32 + quad * 8];
    }
#pragma unroll
    for (int i = 0; i < 4; ++i)
#pragma unroll
      for (int j = 0; j < 4; ++j)
        acc[i][j] = __builtin_amdgcn_mfma_f32_16x16x32_bf16(af[i], bfr[j], acc[i][j], 0, 0, 0);
    __syncthreads();
  }

  // Epilogue: temp/mask/exp -> Cs (bf16), then coalesced E and E^T writes.
  unsigned short* Cs = smem;   // [128][132], safe after final barrier
  const float temp = temp_p[0];
  const int* qmb = qmask + b * LQA;
  const int* amb = amask + b * LQA;
#pragma unroll
  for (int i = 0; i < 4; ++i) {
#pragma unroll
    for (int j = 0; j < 4; ++j) {
      int ncol = noff + j * 16 + lrow;
      float am = (amb[n0 + ncol] != 0) ? 1.f : 0.f;
#pragma unroll
      for (int r = 0; r < 4; ++r) {
        int mrow = moff + i * 16 + quad * 4 + r;
        float qm = (qmb[m0 + mrow] != 0) ? 1.f : 0.f;
        float e = __expf(acc[i][j][r] * temp) * am * qm;
        Cs[mrow * 132 + ncol] = f2bf(e);
      }
    }
  }
  __syncthreads();
  const size_t Ebase = (size_t)b * LQA * LQA;
#pragma unroll
  for (int jj = 0; jj < 16; ++jj) {
    int f = t + 256 * jj;
    int row = f >> 5;            // 0..127
    int c = (f & 31) * 4;        // 0..124
    u16x4 v = *(const u16x4*)&Cs[row * 132 + c];
    *(u16x4*)&E[Ebase + (size_t)(m0 + row) * LQA + n0 + c] = v;
  }
#pragma unroll
  for (int jj = 0; jj < 16; ++jj) {
    int f = t + 256 * jj;
    int orow = f >> 5;           // a-local
    int c = (f & 31) * 4;        // q-local
    u16x4 v;
    v.x = Cs[(c + 0) * 132 + orow];
    v.y = Cs[(c + 1) * 132 + orow];
    v.z = Cs[(c + 2) * 132 + orow];
    v.w = Cs[(c + 3) * 132 + orow];
    *(u16x4*)&ET[Ebase + (size_t)(n0 + orow) * LQA + m0 + c] = v;
  }
}

// ---------------------------------------------------------------------------
// K2a: row sums of bf16 [NROWS x LQA] -> (inv, add) per row.
// inv = 1/sum, add = 0 if sum>0 else inv=0, add=1/1024.  16 rows / 256-block.
// ---------------------------------------------------------------------------
__global__ __launch_bounds__(256) void k_rowsum_stats(
    const unsigned short* __restrict__ Emat, float2* __restrict__ invadd)
{
  const int t = threadIdx.x;
  const int rowg = blockIdx.x * 16 + (t >> 4);
  const int s = t & 15;
  const unsigned short* rp = Emat + (size_t)rowg * LQA;
  float sum = 0.f;
#pragma unroll
  for (int it = 0; it < 16; ++it) {
    u16x4 v = *(const u16x4*)&rp[it * 64 + s * 4];
    sum += bf2f(v.x) + bf2f(v.y) + bf2f(v.z) + bf2f(v.w);
  }
  sum += __shfl_xor(sum, 1);
  sum += __shfl_xor(sum, 2);
  sum += __shfl_xor(sum, 4);
  sum += __shfl_xor(sum, 8);
  if (s == 0) {
    float2 o;
    if (sum > 0.f) { o.x = 1.f / sum; o.y = 0.f; }
    else           { o.x = 0.f;       o.y = 1.f / 1024.f; }
    invadd[rowg] = o;
  }
}

// ---------------------------------------------------------------------------
// K2b: plain row sums of bf16 [NROWS x LQA] -> float. Used on qT/aT to get
// per-(b,h) column sums of q/a (for the all-masked uniform-softmax term).
// ---------------------------------------------------------------------------
__global__ __launch_bounds__(256) void k_rowsum_plain(
    const unsigned short* __restrict__ M, float* __restrict__ sums)
{
  const int t = threadIdx.x;
  const int rowg = blockIdx.x * 16 + (t >> 4);
  const int s = t & 15;
  const unsigned short* rp = M + (size_t)rowg * LQA;
  float sum = 0.f;
#pragma unroll
  for (int it = 0; it < 16; ++it) {
    u16x4 v = *(const u16x4*)&rp[it * 64 + s * 4];
    sum += bf2f(v.x) + bf2f(v.y) + bf2f(v.z) + bf2f(v.w);
  }
  sum += __shfl_xor(sum, 1);
  sum += __shfl_xor(sum, 2);
  sum += __shfl_xor(sum, 4);
  sum += __shfl_xor(sum, 8);
  if (s == 0) sums[rowg] = sum;
}

// ---------------------------------------------------------------------------
// K3: aggregation GEMM (pure bf16, normalization factored into epilogue):
//   out[b,m,512+n] = inv[m] * sum_k Emat[m,k]*Bt[n,k]  +  add[m] * bsum[n]
// Emat: [NB][LQA][LQA] (E or E^T), Bt: [NB][HD][LQA], bsum: [NB][HD].
// grid: (8 mt, 4 nt, NB), block 256
// ---------------------------------------------------------------------------
__global__ __launch_bounds__(256) void k_agg(
    const unsigned short* __restrict__ Emat,
    const unsigned short* __restrict__ Bt,
    const float2* __restrict__ invadd,
    const float* __restrict__ bsum,
    float* __restrict__ outp)
{
  const int b  = blockIdx.z;
  const int m0 = blockIdx.x * 128;
  const int n0 = blockIdx.y * 128;   // h tile (< 512)
  const int t  = threadIdx.x;
  const int lane = t & 63;
  const int w  = t >> 6;
  const int moff = (w & 1) * 64;
  const int noff = (w >> 1) * 64;
  const int lrow = lane & 15;
  const int quad = lane >> 4;

  __shared__ __align__(16) unsigned short As[128 * 32];
  __shared__ __align__(16) unsigned short Bs[128 * 32];

  const unsigned short* Eb = Emat + (size_t)b * LQA * LQA;
  const unsigned short* Bb = Bt + (size_t)b * HD * LQA;

  const int fa = t, fb = t + 256;
  const unsigned short* eg0 = Eb + (size_t)(m0 + (fa >> 2)) * LQA + (fa & 3) * 8;
  const unsigned short* eg1 = Eb + (size_t)(m0 + (fb >> 2)) * LQA + (fb & 3) * 8;
  const unsigned short* bg0 = Bb + (size_t)(n0 + (fa >> 2)) * LQA + (fa & 3) * 8;
  const unsigned short* bg1 = Bb + (size_t)(n0 + (fb >> 2)) * LQA + (fb & 3) * 8;
  unsigned short* As0 = As + w * 512;
  unsigned short* As1 = As + (4 + w) * 512;
  unsigned short* Bs0 = Bs + w * 512;
  unsigned short* Bs1 = Bs + (4 + w) * 512;

  f32x4 acc[4][4];
#pragma unroll
  for (int i = 0; i < 4; ++i)
#pragma unroll
    for (int j = 0; j < 4; ++j) acc[i][j] = (f32x4)0.f;

  for (int kt = 0; kt < LQA / 32; ++kt) {
    const int ko = kt * 32;
    gload_lds16(eg0 + ko, As0);
    gload_lds16(eg1 + ko, As1);
    gload_lds16(bg0 + ko, Bs0);
    gload_lds16(bg1 + ko, Bs1);
    __syncthreads();
    s16x8 af[4], bfr[4];
#pragma unroll
    for (int i = 0; i < 4; ++i) {
      af[i]  = *(const s16x8*)&As[(moff + i * 16 + lrow) * 32 + quad * 8];
      bfr[i] = *(const s16x8*)&Bs[(noff + i * 16 + lrow) * 32 + quad * 8];
    }
#pragma unroll
    for (int i = 0; i < 4; ++i)
#pragma unroll
      for (int j = 0; j < 4; ++j)
        acc[i][j] = __builtin_amdgcn_mfma_f32_16x16x32_bf16(af[i], bfr[j], acc[i][j], 0, 0, 0);
    __syncthreads();
  }

  // Epilogue: normalize + uniform-row term, fp32 stores into concat right half
  const float2* ia = invadd + b * LQA;
  const float* bs = bsum + b * HD;
  float* ob = outp + (size_t)b * LQA * 1024;
#pragma unroll
  for (int i = 0; i < 4; ++i) {
#pragma unroll
    for (int j = 0; j < 4; ++j) {
      int ncol = noff + j * 16 + lrow;
      float bsv = bs[n0 + ncol];
#pragma unroll
      for (int r = 0; r < 4; ++r) {
        int mrow = moff + i * 16 + quad * 4 + r;
        float2 v = ia[m0 + mrow];
        ob[(size_t)(m0 + mrow) * 1024 + 512 + n0 + ncol] =
            v.x * acc[i][j][r] + v.y * bsv;
      }
    }
  }
}

// ---------------------------------------------------------------------------
extern "C" void kernel_launch(void* const* d_in, const int* in_sizes, int n_in,
                              void* d_out, int out_size, void* d_ws, size_t ws_size,
                              hipStream_t stream) {
  (void)in_sizes; (void)n_in; (void)out_size; (void)ws_size;
  const float* q    = (const float*)d_in[0];
  const float* a    = (const float*)d_in[1];
  const int*   qm   = (const int*)d_in[2];
  const int*   am   = (const int*)d_in[3];
  const float* temp = (const float*)d_in[4];

  float* out0 = (float*)d_out;                         // [NB][LQA][1024] concat(q, q_s)
  float* out1 = out0 + (size_t)NB * LQA * 1024;        // [NB][LQA][1024] concat(a, a_s)

  char* ws = (char*)d_ws;
  const size_t MB = 1024ull * 1024ull;
  unsigned short* E    = (unsigned short*)(ws);                 //  64 MB
  unsigned short* ET   = (unsigned short*)(ws + 64 * MB);       //  64 MB
  unsigned short* qT   = (unsigned short*)(ws + 128 * MB);      //  32 MB
  unsigned short* aT   = (unsigned short*)(ws + 160 * MB);      //  32 MB
  unsigned short* qb16 = (unsigned short*)(ws + 192 * MB);      //  32 MB
  unsigned short* ab16 = (unsigned short*)(ws + 224 * MB);      //  32 MB
  float2* invq = (float2*)(ws + 256 * MB);                      // 256 KB
  float2* inva = (float2*)(ws + 256 * MB + 262144);             // 256 KB
  float*  qsum = (float*)(ws + 256 * MB + 524288);              //  64 KB
  float*  asum = (float*)(ws + 256 * MB + 524288 + 65536);      //  64 KB

  k_transpose_copy<<<dim3(8, 16, NB), 256, 0, stream>>>(q, out0, qT, qb16);
  k_transpose_copy<<<dim3(8, 16, NB), 256, 0, stream>>>(a, out1, aT, ab16);
  k_rowsum_plain<<<dim3(NB * HD / 16), 256, 0, stream>>>(qT, qsum);  // sum_q q[:,h]
  k_rowsum_plain<<<dim3(NB * HD / 16), 256, 0, stream>>>(aT, asum);  // sum_a a[:,h]
  k_scores<<<dim3(8, 8, NB), 256, 0, stream>>>(qb16, ab16, qm, am, temp, E, ET);
  k_rowsum_stats<<<dim3(NB * LQA / 16), 256, 0, stream>>>(E, invq);   // per-q over a
  k_rowsum_stats<<<dim3(NB * LQA / 16), 256, 0, stream>>>(ET, inva);  // per-a over q
  k_agg<<<dim3(8, 4, NB), 256, 0, stream>>>(E,  aT, invq, asum, out0);  // q_s
  k_agg<<<dim3(8, 4, NB), 256, 0, stream>>>(ET, qT, inva, qsum, out1);  // a_s
}